// Round 16
// baseline (38.358 us; speedup 1.0000x reference)
//
#include <hip/hip_runtime.h>
#include <stdint.h>

#define IMG  512
#define CPT  8
#define CGRP (IMG / CPT)    // 64 col-groups per row

typedef _Float16 h2    __attribute__((ext_vector_type(2)));
typedef __fp16   f16x2 __attribute__((ext_vector_type(2)));

static __device__ __forceinline__ h2 pkrtz(float a, float b) {
    f16x2 t = __builtin_amdgcn_cvt_pkrtz(a, b);   // v_cvt_pkrtz_f16_f32
    return __builtin_bit_cast(h2, t);
}

#if __has_builtin(__builtin_amdgcn_fdot2)
#define FDOT2(a, b, c) __builtin_amdgcn_fdot2((a), (b), (c), false)
#else
static __device__ __forceinline__ float fdot2_sw(h2 a, h2 b, float c) {
    return fmaf((float)a.x, (float)b.x, fmaf((float)a.y, (float)b.y, c));
}
#define FDOT2(a, b, c) fdot2_sw((a), (b), (c))
#endif

// ws layout (dwords): [0..35] u32 half2 weight pairs u[c][k];
//                     [36..44] w8[c] f32; [45..53] bv[c] f32
__global__ void prepack_kernel(const float* __restrict__ W,
                               const float* __restrict__ B,
                               uint32_t* __restrict__ ws) {
    int c = threadIdx.x;
    if (c < 9) {
        const float* wc = W + c * 9;
#pragma unroll
        for (int k = 0; k < 4; ++k) {
            h2 t = pkrtz(wc[2 * k], wc[2 * k + 1]);
            ws[c * 4 + k] = __builtin_bit_cast(uint32_t, t);
        }
        ((float*)ws)[36 + c] = wc[8];
        ((float*)ws)[45 + c] = B[c];
    }
}

// One 8-pixel output row from 3 input rows. Array references (SROA-safe,
// R7-proven); weights arrive as SGPR-resident u32/f32 arrays (s_loads).
__device__ __forceinline__ void compute8(
    const float (&r0)[10], const float (&r1)[10], const float (&r2)[10],
    const uint32_t (&uu)[9][4], const float (&w8)[9], const float (&bv)[9],
    const float (&lut)[2048], float (&o)[8])
{
    auto tlu = [&](float v) -> float {
        float t = __builtin_amdgcn_fmed3f(fmaf(v, 256.0f, 1024.0f),
                                          0.0f, 2047.0f);
        return lut[(int)t];
    };
#pragma unroll
    for (int tp = 0; tp < 4; ++tp) {
        const int t0 = 2 * tp;
        // f16 K-pairs for pixels t0/t0+1:
        // A=(p0q0,p0q1) B=(p0q2,p1q0) C=(p1q1,p1q2) D=(p2q0,p2q1), lone p2q2 f32
        h2 A0 = pkrtz(r0[t0],     r0[t0 + 1]);
        h2 B0 = pkrtz(r0[t0 + 2], r1[t0]);
        h2 C0 = pkrtz(r1[t0 + 1], r1[t0 + 2]);
        h2 D0 = pkrtz(r2[t0],     r2[t0 + 1]);
        h2 A1 = pkrtz(r0[t0 + 1], r0[t0 + 2]);
        h2 B1 = pkrtz(r0[t0 + 3], r1[t0 + 1]);
        h2 C1 = pkrtz(r1[t0 + 2], r1[t0 + 3]);
        h2 D1 = pkrtz(r2[t0 + 1], r2[t0 + 2]);

        float ox = 0.0f, oy = 0.0f;
#pragma unroll
        for (int c = 0; c < 9; ++c) {
            float fx = bv[c], fy = bv[c];
            fx = FDOT2(A0, __builtin_bit_cast(h2, uu[c][0]), fx);
            fy = FDOT2(A1, __builtin_bit_cast(h2, uu[c][0]), fy);
            fx = FDOT2(B0, __builtin_bit_cast(h2, uu[c][1]), fx);
            fy = FDOT2(B1, __builtin_bit_cast(h2, uu[c][1]), fy);
            fx = FDOT2(C0, __builtin_bit_cast(h2, uu[c][2]), fx);
            fy = FDOT2(C1, __builtin_bit_cast(h2, uu[c][2]), fy);
            fx = FDOT2(D0, __builtin_bit_cast(h2, uu[c][3]), fx);
            fy = FDOT2(D1, __builtin_bit_cast(h2, uu[c][3]), fy);
            fx = fmaf(r2[t0 + 2], w8[c], fx);
            fy = fmaf(r2[t0 + 3], w8[c], fy);

            const float thx = tlu(fx);
            const float thy = tlu(fy);

            const int i = c / 3, j = c - 3 * i;
            const float* rj = (j == 0) ? r0 : (j == 1) ? r1 : r2;
            ox = fmaf(rj[t0 + i],     thx, ox);
            oy = fmaf(rj[t0 + 1 + i], thy, oy);
        }
        o[t0] = ox; o[t0 + 1] = oy;
    }
}

// RPT=2: each thread produces output rows y0,y0+1 from input rows y0-1..y0+2.
// Amortizes LUT fill + weight s_loads over 16 px; fetch 3.75 -> 2.5 floats/px.
__global__ __launch_bounds__(256) void fused_convtap_kernel(
    const float* __restrict__ x,       // (B,1,512,512)
    const uint32_t* __restrict__ wsu,  // prepacked weights
    float* __restrict__ out)           // (B,1,512,512)
{
    __shared__ float lut[2048];

    const int tid = blockIdx.x * 256 + threadIdx.x;
    const int xg  = tid & (CGRP - 1);
    const int rp  = tid >> 6;             // row-pair index: b*256 + y0/2
    const int y0  = (rp & 255) << 1;      // 0,2,..,510
    const int b   = rp >> 8;
    const int x0  = xg * CPT;
    const int rowbase = (b << 9) + y0;

    const float* xr = x + (size_t)rowbase * IMG;
    const bool has_l = (x0 > 0);
    const bool has_r = (x0 < IMG - CPT);

    // ---- issue all 4 row loads FIRST (latency hides under LUT fill) ----
    float r0[10], r1[10], r2[10], r3[10];
    {
        auto load_row = [&](const float* p, float (&r)[10]) {
            float4 a = *reinterpret_cast<const float4*>(p + x0);
            float4 c = *reinterpret_cast<const float4*>(p + x0 + 4);
            r[1] = a.x; r[2] = a.y; r[3] = a.z; r[4] = a.w;
            r[5] = c.x; r[6] = c.y; r[7] = c.z; r[8] = c.w;
            r[0] = has_l ? p[x0 - 1] : 0.0f;
            r[9] = has_r ? p[x0 + 8] : 0.0f;
        };
        auto zero_row = [&](float (&r)[10]) {
#pragma unroll
            for (int k = 0; k < 10; ++k) r[k] = 0.0f;
        };
        if (y0 > 0)        load_row(xr - IMG,     r0); else zero_row(r0);
                           load_row(xr,           r1);
                           load_row(xr + IMG,     r2);   // y0+1 <= 511
        if (y0 < IMG - 2)  load_row(xr + 2 * IMG, r3); else zero_row(r3);
    }

    // ---- geometric LUT fill: 2048 entries, 8/thread, 1 exp2 + 7 mul ----
    {
        const float E2 = 7.38905609893065f;   // e^2 per step of 1.0 in x
        const float xi0 = fmaf((float)threadIdx.x, 0.00390625f,
                               0.001953125f - 4.0f);
        float e = __builtin_amdgcn_exp2f(xi0 * 2.8853900817779268f);
#pragma unroll
        for (int k = 0; k < 8; ++k) {
            lut[threadIdx.x + (k << 8)] =
                1.0f - 2.0f * __builtin_amdgcn_rcpf(e + 1.0f);
            e *= E2;
        }
    }
    __syncthreads();

    // ---- uniform prepacked weights -> SGPRs (saves 36 VGPR vs pkrtz) ----
    uint32_t uu[9][4];
#pragma unroll
    for (int c = 0; c < 9; ++c)
#pragma unroll
        for (int k = 0; k < 4; ++k)
            uu[c][k] = wsu[c * 4 + k];
    float w8[9], bv[9];
    const float* w8v = (const float*)(wsu + 36);
    const float* bvv = (const float*)(wsu + 45);
#pragma unroll
    for (int c = 0; c < 9; ++c) { w8[c] = w8v[c]; bv[c] = bvv[c]; }

    float oA[8], oB[8];
    compute8(r0, r1, r2, uu, w8, bv, lut, oA);   // output row y0
    compute8(r1, r2, r3, uu, w8, bv, lut, oB);   // output row y0+1

    float* orow = out + (size_t)rowbase * IMG + x0;
    *reinterpret_cast<float4*>(orow)           = make_float4(oA[0], oA[1], oA[2], oA[3]);
    *reinterpret_cast<float4*>(orow + 4)       = make_float4(oA[4], oA[5], oA[6], oA[7]);
    *reinterpret_cast<float4*>(orow + IMG)     = make_float4(oB[0], oB[1], oB[2], oB[3]);
    *reinterpret_cast<float4*>(orow + IMG + 4) = make_float4(oB[4], oB[5], oB[6], oB[7]);
}

extern "C" void kernel_launch(void* const* d_in, const int* in_sizes, int n_in,
                              void* d_out, int out_size, void* d_ws, size_t ws_size,
                              hipStream_t stream) {
    const float* x  = (const float*)d_in[0];   // (B,1,512,512) f32
    const float* W  = (const float*)d_in[1];   // (9,1,3,3)     f32
    const float* Bv = (const float*)d_in[2];   // (9,)          f32
    float* out = (float*)d_out;
    uint32_t* ws = (uint32_t*)d_ws;

    prepack_kernel<<<1, 64, 0, stream>>>(W, Bv, ws);

    const int batch   = in_sizes[0] / (IMG * IMG);       // 32
    const int threads = batch * (IMG / 2) * CGRP;        // 524288
    const int grid    = threads / 256;                   // 2048
    fused_convtap_kernel<<<grid, 256, 0, stream>>>(x, ws, out);
}

// Round 17
// 38.198 us; speedup vs baseline: 1.0042x; 1.0042x over previous
//
#include <hip/hip_runtime.h>
#include <stdint.h>

#define IMG  512
#define CPT  8
#define CGRP (IMG / CPT)    // 64 col-groups per row

typedef _Float16 h2    __attribute__((ext_vector_type(2)));
typedef __fp16   f16x2 __attribute__((ext_vector_type(2)));

static __device__ __forceinline__ h2 pkrtz(float a, float b) {
    f16x2 t = __builtin_amdgcn_cvt_pkrtz(a, b);   // v_cvt_pkrtz_f16_f32
    return __builtin_bit_cast(h2, t);
}

#if __has_builtin(__builtin_amdgcn_fdot2)
#define FDOT2(a, b, c) __builtin_amdgcn_fdot2((a), (b), (c), false)
#else
static __device__ __forceinline__ float fdot2_sw(h2 a, h2 b, float c) {
    return fmaf((float)a.x, (float)b.x, fmaf((float)a.y, (float)b.y, c));
}
#define FDOT2(a, b, c) fdot2_sw((a), (b), (c))
#endif

// R15 structure (34.8us) + pipe-balancing: per-CU accounting showed the LDS
// pipe (9 random-index LUT reads/px at ~3.4cy avg from 64-ball/32-bank
// max-load conflicts) is the largest pipe (~13us) while TRANS sits idle.
// Channels {1,3,5,7} use exp2-form tanh (TRANS pipe); {0,2,4,6,8} use the
// LDS LUT. Both pipes land ~7us, under VALU (~11us).

__global__ __launch_bounds__(256) void fused_convtap_kernel(
    const float* __restrict__ x,   // (B,1,512,512)
    const float* __restrict__ W,   // (9,1,3,3)
    const float* __restrict__ Bv,  // (9,)
    float* __restrict__ out)       // (B,1,512,512)
{
    __shared__ float lut[2048];

    const int tid = blockIdx.x * 256 + threadIdx.x;
    const int xg  = tid & (CGRP - 1);
    const int row = tid >> 6;            // b*IMG + y
    const int y   = row & (IMG - 1);
    const int x0  = xg * CPT;

    const float* xr = x + (size_t)row * IMG;
    const bool has_l = (x0 > 0);
    const bool has_r = (x0 < IMG - CPT);

    // ---- issue global row loads FIRST (latency hides under LUT fill) ----
    float r0[10], r1[10], r2[10];
    {
        auto load_row = [&](const float* p, float (&r)[10]) {
            float4 a = *reinterpret_cast<const float4*>(p + x0);
            float4 c = *reinterpret_cast<const float4*>(p + x0 + 4);
            r[1] = a.x; r[2] = a.y; r[3] = a.z; r[4] = a.w;
            r[5] = c.x; r[6] = c.y; r[7] = c.z; r[8] = c.w;
            r[0] = has_l ? p[x0 - 1] : 0.0f;
            r[9] = has_r ? p[x0 + 8] : 0.0f;
        };
        auto zero_row = [&](float (&r)[10]) {
#pragma unroll
            for (int k = 0; k < 10; ++k) r[k] = 0.0f;
        };
        if (y > 0)       load_row(xr - IMG, r0); else zero_row(r0);
                         load_row(xr,       r1);
        if (y < IMG - 1) load_row(xr + IMG, r2); else zero_row(r2);
    }

    // ---- geometric LUT fill: entry i = tanh((i+0.5)/256 - 4) ----
    {
        const float E2 = 7.38905609893065f;   // e^2 per x-step of 1.0
        const float xi0 = fmaf((float)threadIdx.x, 0.00390625f,
                               0.001953125f - 4.0f);
        float e = __builtin_amdgcn_exp2f(xi0 * 2.8853900817779268f);
#pragma unroll
        for (int k = 0; k < 8; ++k) {
            lut[threadIdx.x + (k << 8)] =
                1.0f - 2.0f * __builtin_amdgcn_rcpf(e + 1.0f);
            e *= E2;
        }
    }
    __syncthreads();

    // Uniform weights (s_loads); f16 pairs built per-thread.
    h2 u[9][4];
    float w8[9], bv[9];
#pragma unroll
    for (int c = 0; c < 9; ++c) {
#pragma unroll
        for (int k = 0; k < 4; ++k)
            u[c][k] = pkrtz(W[c * 9 + 2 * k], W[c * 9 + 2 * k + 1]);
        w8[c] = W[c * 9 + 8];
        bv[c] = Bv[c];
    }

    // LDS-pipe tanh: clamp+floor index into block-local LUT.
    auto tlu = [&](float v) -> float {
        float t = __builtin_amdgcn_fmed3f(fmaf(v, 256.0f, 1024.0f),
                                          0.0f, 2047.0f);
        return lut[(int)t];
    };
    // TRANS-pipe tanh: 1 - 2/(exp2(v*2log2e)+1). Saturates correctly.
    auto texp = [&](float v) -> float {
        float e = __builtin_amdgcn_exp2f(v * 2.8853900817779268f);
        return fmaf(-2.0f, __builtin_amdgcn_rcpf(e + 1.0f), 1.0f);
    };

    float o[CPT];
#pragma unroll
    for (int tp = 0; tp < 4; ++tp) {
        const int t0 = 2 * tp;
        // f16 K-pairs for pixels t0/t0+1:
        // A=(p0q0,p0q1) B=(p0q2,p1q0) C=(p1q1,p1q2) D=(p2q0,p2q1), lone p2q2 f32
        h2 A0 = pkrtz(r0[t0],     r0[t0 + 1]);
        h2 B0 = pkrtz(r0[t0 + 2], r1[t0]);
        h2 C0 = pkrtz(r1[t0 + 1], r1[t0 + 2]);
        h2 D0 = pkrtz(r2[t0],     r2[t0 + 1]);
        h2 A1 = pkrtz(r0[t0 + 1], r0[t0 + 2]);
        h2 B1 = pkrtz(r0[t0 + 3], r1[t0 + 1]);
        h2 C1 = pkrtz(r1[t0 + 2], r1[t0 + 3]);
        h2 D1 = pkrtz(r2[t0 + 1], r2[t0 + 2]);

        float ox = 0.0f, oy = 0.0f;
#pragma unroll
        for (int c = 0; c < 9; ++c) {
            float fx = bv[c], fy = bv[c];
            fx = FDOT2(A0, u[c][0], fx);
            fy = FDOT2(A1, u[c][0], fy);
            fx = FDOT2(B0, u[c][1], fx);
            fy = FDOT2(B1, u[c][1], fy);
            fx = FDOT2(C0, u[c][2], fx);
            fy = FDOT2(C1, u[c][2], fy);
            fx = FDOT2(D0, u[c][3], fx);
            fy = FDOT2(D1, u[c][3], fy);
            fx = fmaf(r2[t0 + 2], w8[c], fx);
            fy = fmaf(r2[t0 + 3], w8[c], fy);

            // Pipe split: odd channels 1,3,5,7 -> TRANS; evens -> LDS LUT.
            const bool use_trans = (c & 1);
            const float thx = use_trans ? texp(fx) : tlu(fx);
            const float thy = use_trans ? texp(fy) : tlu(fy);

            // tap stage: out += patch[j][i] * tanh(fc_c), c = 3i+j
            const int i = c / 3, j = c - 3 * i;
            const float* rj = (j == 0) ? r0 : (j == 1) ? r1 : r2;
            ox = fmaf(rj[t0 + i],     thx, ox);
            oy = fmaf(rj[t0 + 1 + i], thy, oy);
        }
        o[t0] = ox; o[t0 + 1] = oy;
    }

    float* orow = out + (size_t)row * IMG + x0;
    *reinterpret_cast<float4*>(orow)     = make_float4(o[0], o[1], o[2], o[3]);
    *reinterpret_cast<float4*>(orow + 4) = make_float4(o[4], o[5], o[6], o[7]);
}

extern "C" void kernel_launch(void* const* d_in, const int* in_sizes, int n_in,
                              void* d_out, int out_size, void* d_ws, size_t ws_size,
                              hipStream_t stream) {
    const float* x  = (const float*)d_in[0];   // (B,1,512,512) f32
    const float* W  = (const float*)d_in[1];   // (9,1,3,3)     f32
    const float* Bv = (const float*)d_in[2];   // (9,)          f32
    float* out = (float*)d_out;

    const int batch   = in_sizes[0] / (IMG * IMG);   // 32
    const int threads = batch * IMG * CGRP;          // 1,048,576
    const int grid    = threads / 256;               // 4096
    fused_convtap_kernel<<<grid, 256, 0, stream>>>(x, W, Bv, out);
}

// Round 18
// 34.671 us; speedup vs baseline: 1.1063x; 1.1017x over previous
//
#include <hip/hip_runtime.h>
#include <stdint.h>

#define IMG  512
#define CPT  8
#define CGRP (IMG / CPT)    // 64 col-groups per row

typedef _Float16 h2    __attribute__((ext_vector_type(2)));
typedef __fp16   f16x2 __attribute__((ext_vector_type(2)));

static __device__ __forceinline__ h2 pkrtz(float a, float b) {
    f16x2 t = __builtin_amdgcn_cvt_pkrtz(a, b);   // v_cvt_pkrtz_f16_f32
    return __builtin_bit_cast(h2, t);
}

#if __has_builtin(__builtin_amdgcn_fdot2)
#define FDOT2(a, b, c) __builtin_amdgcn_fdot2((a), (b), (c), false)
#else
static __device__ __forceinline__ float fdot2_sw(h2 a, h2 b, float c) {
    return fmaf((float)a.x, (float)b.x, fmaf((float)a.y, (float)b.y, c));
}
#define FDOT2(a, b, c) fdot2_sw((a), (b), (c))
#endif

// R15 (34.8us best) + index-fold: conv weights/bias pre-scaled by 1024 (=2^10,
// EXACT in f16/f32) with +4096 in the bias, so the dot2 accumulator is
// directly the LUT *byte* index: lookup = med3 + cvt + and + ds_read (3 VALU),
// and the 72 per-thread index fmas disappear. -144 VALU on the dependent
// conv->tap path (~10% of wave issue).
// LUT: entry i = tanh((i+0.5)/256 - 4); byte idx = fc*1024 + 4096, clamped
// to [0, 8188], floored to a multiple of 4.

__global__ __launch_bounds__(256) void fused_convtap_kernel(
    const float* __restrict__ x,   // (B,1,512,512)
    const float* __restrict__ W,   // (9,1,3,3)
    const float* __restrict__ Bv,  // (9,)
    float* __restrict__ out)       // (B,1,512,512)
{
    __shared__ float lut[2048];

    const int tid = blockIdx.x * 256 + threadIdx.x;
    const int xg  = tid & (CGRP - 1);
    const int row = tid >> 6;            // b*IMG + y
    const int y   = row & (IMG - 1);
    const int x0  = xg * CPT;

    const float* xr = x + (size_t)row * IMG;
    const bool has_l = (x0 > 0);
    const bool has_r = (x0 < IMG - CPT);

    // ---- issue global row loads FIRST (latency hides under LUT fill) ----
    float r0[10], r1[10], r2[10];
    {
        auto load_row = [&](const float* p, float (&r)[10]) {
            float4 a = *reinterpret_cast<const float4*>(p + x0);
            float4 c = *reinterpret_cast<const float4*>(p + x0 + 4);
            r[1] = a.x; r[2] = a.y; r[3] = a.z; r[4] = a.w;
            r[5] = c.x; r[6] = c.y; r[7] = c.z; r[8] = c.w;
            r[0] = has_l ? p[x0 - 1] : 0.0f;
            r[9] = has_r ? p[x0 + 8] : 0.0f;
        };
        auto zero_row = [&](float (&r)[10]) {
#pragma unroll
            for (int k = 0; k < 10; ++k) r[k] = 0.0f;
        };
        if (y > 0)       load_row(xr - IMG, r0); else zero_row(r0);
                         load_row(xr,       r1);
        if (y < IMG - 1) load_row(xr + IMG, r2); else zero_row(r2);
    }

    // ---- geometric LUT fill: entry i = tanh((i+0.5)/256 - 4) ----
    {
        const float E2 = 7.38905609893065f;   // e^2 per x-step of 1.0
        const float xi0 = fmaf((float)threadIdx.x, 0.00390625f,
                               0.001953125f - 4.0f);
        float e = __builtin_amdgcn_exp2f(xi0 * 2.8853900817779268f);
#pragma unroll
        for (int k = 0; k < 8; ++k) {
            lut[threadIdx.x + (k << 8)] =
                1.0f - 2.0f * __builtin_amdgcn_rcpf(e + 1.0f);
            e *= E2;
        }
    }
    __syncthreads();

    // Uniform weights scaled by 1024 (exact); bias*1024 + 4096.
    h2 u[9][4];
    float w8[9], bv[9];
#pragma unroll
    for (int c = 0; c < 9; ++c) {
#pragma unroll
        for (int k = 0; k < 4; ++k)
            u[c][k] = pkrtz(W[c * 9 + 2 * k] * 1024.0f,
                            W[c * 9 + 2 * k + 1] * 1024.0f);
        w8[c] = W[c * 9 + 8] * 1024.0f;
        bv[c] = fmaf(Bv[c], 1024.0f, 4096.0f);
    }

    // tanh lookup from byte-index accumulator: med3 + cvt + and + ds_read.
    const char* lutb = (const char*)lut;
    auto tlu = [&](float v) -> float {
        float t = __builtin_amdgcn_fmed3f(v, 0.0f, 8188.0f);
        int   i = ((int)t) & ~3;
        return *(const float*)(lutb + i);
    };

    float o[CPT];
#pragma unroll
    for (int tp = 0; tp < 4; ++tp) {
        const int t0 = 2 * tp;
        // f16 K-pairs for pixels t0/t0+1:
        // A=(p0q0,p0q1) B=(p0q2,p1q0) C=(p1q1,p1q2) D=(p2q0,p2q1), lone p2q2 f32
        h2 A0 = pkrtz(r0[t0],     r0[t0 + 1]);
        h2 B0 = pkrtz(r0[t0 + 2], r1[t0]);
        h2 C0 = pkrtz(r1[t0 + 1], r1[t0 + 2]);
        h2 D0 = pkrtz(r2[t0],     r2[t0 + 1]);
        h2 A1 = pkrtz(r0[t0 + 1], r0[t0 + 2]);
        h2 B1 = pkrtz(r0[t0 + 3], r1[t0 + 1]);
        h2 C1 = pkrtz(r1[t0 + 2], r1[t0 + 3]);
        h2 D1 = pkrtz(r2[t0 + 1], r2[t0 + 2]);

        float ox = 0.0f, oy = 0.0f;
#pragma unroll
        for (int c = 0; c < 9; ++c) {
            float fx = bv[c], fy = bv[c];
            fx = FDOT2(A0, u[c][0], fx);
            fy = FDOT2(A1, u[c][0], fy);
            fx = FDOT2(B0, u[c][1], fx);
            fy = FDOT2(B1, u[c][1], fy);
            fx = FDOT2(C0, u[c][2], fx);
            fy = FDOT2(C1, u[c][2], fy);
            fx = FDOT2(D0, u[c][3], fx);
            fy = FDOT2(D1, u[c][3], fy);
            fx = fmaf(r2[t0 + 2], w8[c], fx);
            fy = fmaf(r2[t0 + 3], w8[c], fy);

            const float thx = tlu(fx);
            const float thy = tlu(fy);

            // tap stage: out += patch[j][i] * tanh(fc_c), c = 3i+j
            const int i = c / 3, j = c - 3 * i;
            const float* rj = (j == 0) ? r0 : (j == 1) ? r1 : r2;
            ox = fmaf(rj[t0 + i],     thx, ox);
            oy = fmaf(rj[t0 + 1 + i], thy, oy);
        }
        o[t0] = ox; o[t0 + 1] = oy;
    }

    float* orow = out + (size_t)row * IMG + x0;
    *reinterpret_cast<float4*>(orow)     = make_float4(o[0], o[1], o[2], o[3]);
    *reinterpret_cast<float4*>(orow + 4) = make_float4(o[4], o[5], o[6], o[7]);
}

extern "C" void kernel_launch(void* const* d_in, const int* in_sizes, int n_in,
                              void* d_out, int out_size, void* d_ws, size_t ws_size,
                              hipStream_t stream) {
    const float* x  = (const float*)d_in[0];   // (B,1,512,512) f32
    const float* W  = (const float*)d_in[1];   // (9,1,3,3)     f32
    const float* Bv = (const float*)d_in[2];   // (9,)          f32
    float* out = (float*)d_out;

    const int batch   = in_sizes[0] / (IMG * IMG);   // 32
    const int threads = batch * IMG * CGRP;          // 1,048,576
    const int grid    = threads / 256;               // 4096
    fused_convtap_kernel<<<grid, 256, 0, stream>>>(x, W, Bv, out);
}